// Round 1
// baseline (162.844 us; speedup 1.0000x reference)
//
#include <hip/hip_runtime.h>

// Problem constants (setup_inputs is fixed):
//   B=16, N=2048, C=128, S=25, D_AGG=128, D_OUT=128
// in order: A[16,2048,2048] f32, X[16,2048,128] f32, Wa[128,128] f32,
//           ba[128] f32, Wc[256,128] f32, bc[128] f32, n_samples=25 (i32)
// out: [16,2048,128] f32 (4,194,304 elements)
//
// ws layout: agg [32768,128] f32 @ 0 (16 MB); partials[512] f32 @ 16 MB;
//            scales[16] f32 after that. Total ~16.01 MB.
// d_out doubles as scratch for H = relu(X@Wa+ba) (exactly 16 MB), consumed
// by the scan kernel and then fully overwritten by the second GEMM.

constexpr int NPB   = 2048;     // nodes per batch
constexpr int CDIM  = 128;

// ---------------------------------------------------------------------------
// K1/K3: out[row,:] = relu(src(row,:) @ W + bias), src = [src0 | src1] k-tiles
// 64-row tile per block, 256 threads, 8 rows x 4 cols per thread.
// Optionally emits per-block sum of squares (for the Frobenius norm).
// ---------------------------------------------------------------------------
__global__ __launch_bounds__(256) void gemm_relu_k(
    const float* __restrict__ src0,
    const float* __restrict__ src1,     // second 128-wide k-tile (or nullptr)
    const float* __restrict__ W,        // [ktiles*128, 128] row-major
    const float* __restrict__ bias,     // [128]
    float* __restrict__ out,            // [32768, 128]
    float* __restrict__ partials,       // [gridDim.x] sumsq, or nullptr
    int ktiles)
{
    __shared__ float Xs[64][128];
    __shared__ float wred[4];
    const int tid = threadIdx.x;
    const int tx  = tid & 31;           // column quad: cols tx*4 .. tx*4+3
    const int ty  = tid >> 5;           // row group: rows ty*8 .. ty*8+7
    const size_t row0 = (size_t)blockIdx.x * 64;

    float4 acc[8];
#pragma unroll
    for (int i = 0; i < 8; ++i) acc[i] = make_float4(0.f, 0.f, 0.f, 0.f);

    for (int t = 0; t < ktiles; ++t) {
        const float* src = (t == 0) ? src0 : src1;
        __syncthreads();
#pragma unroll
        for (int i = 0; i < 8; ++i) {
            int r = ty + i * 8;
            *(float4*)&Xs[r][tx * 4] =
                *(const float4*)&src[(row0 + r) * CDIM + tx * 4];
        }
        __syncthreads();
        for (int k = 0; k < 128; ++k) {
            float4 w = *(const float4*)&W[(size_t)(t * 128 + k) * 128 + tx * 4];
#pragma unroll
            for (int i = 0; i < 8; ++i) {
                float x = Xs[ty * 8 + i][k];
                acc[i].x = fmaf(x, w.x, acc[i].x);
                acc[i].y = fmaf(x, w.y, acc[i].y);
                acc[i].z = fmaf(x, w.z, acc[i].z);
                acc[i].w = fmaf(x, w.w, acc[i].w);
            }
        }
    }

    float4 bb = *(const float4*)&bias[tx * 4];
    float lsum = 0.f;
#pragma unroll
    for (int i = 0; i < 8; ++i) {
        float4 v = acc[i];
        v.x = fmaxf(v.x + bb.x, 0.f);
        v.y = fmaxf(v.y + bb.y, 0.f);
        v.z = fmaxf(v.z + bb.z, 0.f);
        v.w = fmaxf(v.w + bb.w, 0.f);
        size_t row = row0 + (size_t)ty * 8 + i;
        *(float4*)&out[row * 128 + tx * 4] = v;
        lsum += v.x * v.x + v.y * v.y + v.z * v.z + v.w * v.w;
    }

    if (partials) {
#pragma unroll
        for (int off = 32; off > 0; off >>= 1)
            lsum += __shfl_down(lsum, off, 64);
        if ((tid & 63) == 0) wred[tid >> 6] = lsum;
        __syncthreads();
        if (tid == 0)
            partials[blockIdx.x] = wred[0] + wred[1] + wred[2] + wred[3];
    }
}

// ---------------------------------------------------------------------------
// K2: per node, scan A row for the first min(deg,S) nonzero indices
// (== lax.top_k of a binary mask: ascending index order) and elementwise-max
// the corresponding rows of H. acc init = relu(ba) == padded-slot value.
// One wave per node; 4 waves per block. Ballot results are wave-uniform so
// all control flow is uniform.
// ---------------------------------------------------------------------------
__global__ __launch_bounds__(256) void agg_k(
    const float* __restrict__ A,       // [32768, 2048]
    const float* __restrict__ H,       // [32768, 128] (lives in d_out)
    const float* __restrict__ ba,      // [128]
    float* __restrict__ agg,           // [32768, 128]
    const int* __restrict__ nsp)       // n_samples (25)
{
    const int lane = threadIdx.x & 63;
    const int widx = threadIdx.x >> 6;
    const int node = blockIdx.x * 4 + widx;     // 0..32767
    const int b    = node >> 11;                // node / 2048
    const int S    = nsp[0];

    // Prefetch full 8 KB row: 8 float4 per lane, all in flight at once.
    const float4* row = (const float4*)(A + (size_t)node * NPB);
    float4 v[8];
#pragma unroll
    for (int c = 0; c < 8; ++c) v[c] = row[c * 64 + lane];

    float acc0 = fmaxf(ba[lane], 0.f);
    float acc1 = fmaxf(ba[64 + lane], 0.f);
    const float* Hb = H + ((size_t)b << 11) * CDIM;

    int found = 0;
#pragma unroll
    for (int c = 0; c < 8; ++c) {               // fully unrolled: v[] static
        if (found < S) {
            unsigned long long m0 = __ballot(v[c].x != 0.f);
            unsigned long long m1 = __ballot(v[c].y != 0.f);
            unsigned long long m2 = __ballot(v[c].z != 0.f);
            unsigned long long m3 = __ballot(v[c].w != 0.f);
            unsigned long long any = m0 | m1 | m2 | m3;
            while (any != 0ull && found < S) {
                int l = __builtin_ctzll(any);
                any &= any - 1;
                unsigned long long bit = 1ull << l;
                int jb = c * 256 + l * 4;       // element = 256c + 4*lane + comp
                if ((m0 & bit) && found < S) {
                    const float* hr = Hb + (size_t)(jb + 0) * CDIM;
                    acc0 = fmaxf(acc0, hr[lane]);
                    acc1 = fmaxf(acc1, hr[64 + lane]);
                    ++found;
                }
                if ((m1 & bit) && found < S) {
                    const float* hr = Hb + (size_t)(jb + 1) * CDIM;
                    acc0 = fmaxf(acc0, hr[lane]);
                    acc1 = fmaxf(acc1, hr[64 + lane]);
                    ++found;
                }
                if ((m2 & bit) && found < S) {
                    const float* hr = Hb + (size_t)(jb + 2) * CDIM;
                    acc0 = fmaxf(acc0, hr[lane]);
                    acc1 = fmaxf(acc1, hr[64 + lane]);
                    ++found;
                }
                if ((m3 & bit) && found < S) {
                    const float* hr = Hb + (size_t)(jb + 3) * CDIM;
                    acc0 = fmaxf(acc0, hr[lane]);
                    acc1 = fmaxf(acc1, hr[64 + lane]);
                    ++found;
                }
            }
        }
    }

    agg[(size_t)node * CDIM + lane]      = acc0;
    agg[(size_t)node * CDIM + 64 + lane] = acc1;
}

// ---------------------------------------------------------------------------
// K4: per-batch scale = norm > 0 ? 1/norm : 0  (div_no_nan semantics).
// Deterministic serial reduction of 32 block-partials per batch.
// ---------------------------------------------------------------------------
__global__ __launch_bounds__(64) void scales_k(
    const float* __restrict__ partials,   // [512], 32 per batch
    float* __restrict__ scales)           // [16]
{
    int t = threadIdx.x;
    if (t < 16) {
        float s = 0.f;
        for (int i = 0; i < 32; ++i) s += partials[t * 32 + i];
        float norm = sqrtf(s);
        scales[t] = (norm > 0.f) ? (1.f / norm) : 0.f;
    }
}

// ---------------------------------------------------------------------------
// K5: out *= scale[batch], in place. 1M float4; batch = float4_idx >> 16.
// ---------------------------------------------------------------------------
__global__ __launch_bounds__(256) void scale_k(
    float* __restrict__ out, const float* __restrict__ scales)
{
    const int total4 = 1 << 20;
    for (int i = blockIdx.x * blockDim.x + threadIdx.x; i < total4;
         i += gridDim.x * blockDim.x) {
        float s = scales[i >> 16];
        float4 v = ((const float4*)out)[i];
        v.x *= s; v.y *= s; v.z *= s; v.w *= s;
        ((float4*)out)[i] = v;
    }
}

extern "C" void kernel_launch(void* const* d_in, const int* in_sizes, int n_in,
                              void* d_out, int out_size, void* d_ws, size_t ws_size,
                              hipStream_t stream) {
    const float* A  = (const float*)d_in[0];
    const float* X  = (const float*)d_in[1];
    const float* Wa = (const float*)d_in[2];
    const float* ba = (const float*)d_in[3];
    const float* Wc = (const float*)d_in[4];
    const float* bc = (const float*)d_in[5];
    const int*  nsp = (const int*)d_in[6];

    float* out      = (float*)d_out;
    float* agg      = (float*)d_ws;                              // 16 MB
    float* partials = (float*)((char*)d_ws + (16u << 20));       // 2 KB
    float* scales   = partials + 512;                            // 64 B

    // K1: H = relu(X @ Wa + ba) -> d_out (scratch; overwritten by K3)
    gemm_relu_k<<<512, 256, 0, stream>>>(X, nullptr, Wa, ba, out, nullptr, 1);
    // K2: agg = max over first-S neighbors of H rows
    agg_k<<<8192, 256, 0, stream>>>(A, out, ba, agg, nsp);
    // K3: out = relu([X, agg] @ Wc + bc) + per-block sumsq partials
    gemm_relu_k<<<512, 256, 0, stream>>>(X, agg, Wc, bc, out, partials, 2);
    // K4: per-batch scale
    scales_k<<<1, 64, 0, stream>>>(partials, scales);
    // K5: normalize in place
    scale_k<<<1024, 256, 0, stream>>>(out, scales);
}

// Round 2
// 97.137 us; speedup vs baseline: 1.6764x; 1.6764x over previous
//
#include <hip/hip_runtime.h>

// B=16, N=2048, C=128, S=25, D_AGG=128, D_OUT=128
// in: A[16,2048,2048] f32, X[16,2048,128] f32, Wa[128,128] f32, ba[128] f32,
//     Wc[256,128] f32, bc[128] f32, n_samples i32
// out: [16,2048,128] f32
//
// Pipeline (all bf16 MFMA for the two GEMMs):
//   prep_w : Wa -> Wat[d][k] bf16 (transposed), Wc -> Wct[d][k=0..255] bf16
//   K1     : H  = relu(X @ Wa + ba)  -> bf16 [32768][128]    (MFMA)
//   K2     : agg = max over first-S neighbors of H rows -> bf16 (ballot scan)
//   K3     : out = relu([X|agg] @ Wc + bc) -> f32 d_out + partials (MFMA)
//   K5     : out *= 1/frobnorm (per batch, div_no_nan), partials reduced in-block
//
// ws: H 8MB @0, agg 8MB @8M, Wat 32KB @16M, Wct 64KB @16M+32K, partials @16M+128K

typedef __attribute__((ext_vector_type(8))) short short8;   // bf16x8 raw bits
typedef __attribute__((ext_vector_type(4))) float f32x4;
typedef __attribute__((ext_vector_type(4))) float fvec4;
typedef unsigned int uint;
typedef unsigned short ushort;

__device__ __forceinline__ ushort f2bf(float x) {           // RNE f32->bf16
    uint u = __builtin_bit_cast(uint, x);
    u += 0x7FFFu + ((u >> 16) & 1u);
    return (ushort)(u >> 16);
}
__device__ __forceinline__ float bflo(uint h) { uint v = h << 16;         return __builtin_bit_cast(float, v); }
__device__ __forceinline__ float bfhi(uint h) { uint v = h & 0xFFFF0000u; return __builtin_bit_cast(float, v); }

// ---------------------------------------------------------------------------
// prep_w: convert + transpose weights to bf16 [out_col][k]
// ---------------------------------------------------------------------------
__global__ __launch_bounds__(256) void prep_w_k(
    const float* __restrict__ Wa, const float* __restrict__ Wc,
    ushort* __restrict__ Wat, ushort* __restrict__ Wct)
{
    int i = blockIdx.x * 256 + threadIdx.x;
    if (i < 16384) {                       // Wat[d*128+k] = Wa[k][d]
        int d = i >> 7, k = i & 127;
        Wat[i] = f2bf(Wa[k * 128 + d]);
    } else {                               // Wct[d*256+k] = Wc[k][d]
        int j = i - 16384;                 // j < 32768
        int d = j >> 8, k = j & 255;
        Wct[j] = f2bf(Wc[k * 128 + d]);
    }
}

// ---------------------------------------------------------------------------
// MFMA GEMM: 128-row x 128-col tile per block, 4 waves in 2x2, each wave a
// 64x64 subtile = 4x4 frags of 16x16x32. A chunk0 converted from fp32 X,
// chunk1 (K3 only) copied from bf16 agg. B = pre-transposed bf16 [col][k].
// LDS XOR swizzle on 16B granules: g ^= (row&7)  (write AND read sides).
// ---------------------------------------------------------------------------
__global__ __launch_bounds__(256) void gemm_mfma_k(
    const float*  __restrict__ Xf,       // fp32 A source, chunk 0
    const ushort* __restrict__ A1,       // bf16 A source, chunk 1 (or null)
    const ushort* __restrict__ Bt,       // [128][KT] bf16
    const float*  __restrict__ bias,     // [128]
    ushort* __restrict__ outH,           // bf16 out (K1) or null
    float*  __restrict__ outF,           // f32 out (K3) or null
    float*  __restrict__ partials,       // [gridDim.x] sumsq or null
    int ktiles)
{
    __shared__ ushort Asm[128 * 128];
    __shared__ ushort Bsm[128 * 128];
    __shared__ float wred[4];
    const int tid = threadIdx.x;
    const int l = tid & 63, w = tid >> 6;
    const int wm = (w >> 1) * 64, wn = (w & 1) * 64;
    const size_t row0 = (size_t)blockIdx.x * 128;
    const int KT = ktiles << 7;

    f32x4 acc[4][4] = {};

    for (int t = 0; t < ktiles; ++t) {
        __syncthreads();
        if (t == 0) {
#pragma unroll
            for (int j = 0; j < 8; ++j) {
                int gid = (j << 8) + tid;          // 16B granule id
                int r = gid >> 4, g = gid & 15;
                const float* s = Xf + (row0 + r) * 128 + g * 8;
                short8 pk;
#pragma unroll
                for (int e = 0; e < 8; ++e) pk[e] = (short)f2bf(s[e]);
                *(short8*)&Asm[r * 128 + ((g ^ (r & 7)) << 3)] = pk;
            }
        } else {
#pragma unroll
            for (int j = 0; j < 8; ++j) {
                int gid = (j << 8) + tid;
                int r = gid >> 4, g = gid & 15;
                short8 v = *(const short8*)(A1 + (row0 + r) * 128 + g * 8);
                *(short8*)&Asm[r * 128 + ((g ^ (r & 7)) << 3)] = v;
            }
        }
#pragma unroll
        for (int j = 0; j < 8; ++j) {
            int gid = (j << 8) + tid;
            int r = gid >> 4, g = gid & 15;
            short8 v = *(const short8*)(Bt + (size_t)r * KT + (t << 7) + g * 8);
            *(short8*)&Bsm[r * 128 + ((g ^ (r & 7)) << 3)] = v;
        }
        __syncthreads();
#pragma unroll
        for (int ks = 0; ks < 4; ++ks) {
            int gg = (ks << 2) + (l >> 4);
            short8 af[4], bfr[4];
#pragma unroll
            for (int m = 0; m < 4; ++m) {
                int r = wm + m * 16 + (l & 15);
                af[m] = *(const short8*)&Asm[r * 128 + ((gg ^ (r & 7)) << 3)];
            }
#pragma unroll
            for (int n = 0; n < 4; ++n) {
                int c = wn + n * 16 + (l & 15);
                bfr[n] = *(const short8*)&Bsm[c * 128 + ((gg ^ (c & 7)) << 3)];
            }
#pragma unroll
            for (int m = 0; m < 4; ++m)
#pragma unroll
                for (int n = 0; n < 4; ++n)
                    acc[m][n] = __builtin_amdgcn_mfma_f32_16x16x32_bf16(
                        af[m], bfr[n], acc[m][n], 0, 0, 0);
        }
    }

    float bcol[4];
#pragma unroll
    for (int n = 0; n < 4; ++n) bcol[n] = bias[wn + n * 16 + (l & 15)];
    float lsum = 0.f;
#pragma unroll
    for (int m = 0; m < 4; ++m) {
        int rbase = wm + m * 16 + ((l >> 4) << 2);   // C/D: row = 4*(l>>4)+reg
#pragma unroll
        for (int n = 0; n < 4; ++n) {
            int col = wn + n * 16 + (l & 15);        // C/D: col = l&15
#pragma unroll
            for (int r = 0; r < 4; ++r) {
                float v = fmaxf(acc[m][n][r] + bcol[n], 0.f);
                size_t o = (row0 + rbase + r) * 128 + col;
                if (outH) outH[o] = f2bf(v);
                else { outF[o] = v; lsum += v * v; }
            }
        }
    }
    if (partials) {
#pragma unroll
        for (int off = 32; off > 0; off >>= 1) lsum += __shfl_down(lsum, off);
        if (l == 0) wred[w] = lsum;
        __syncthreads();
        if (tid == 0) partials[blockIdx.x] = wred[0] + wred[1] + wred[2] + wred[3];
    }
}

// ---------------------------------------------------------------------------
// K2: one wave per node. Phase 1: ballot-scan A row, first min(deg,S) indices
// to LDS. Phase 2: 4-deep pipelined bf16 gather-max of H rows.
// acc init = relu(ba) == padded-slot value. A loads nontemporal (no reuse).
// ---------------------------------------------------------------------------
__global__ __launch_bounds__(256) void agg_k(
    const float* __restrict__ A,        // [32768][2048]
    const uint*  __restrict__ Hu,       // [32768][64] (bf16 pairs)
    const float* __restrict__ ba,
    uint* __restrict__ aggu,            // [32768][64] (bf16 pairs)
    const int* __restrict__ nsp)
{
    __shared__ int idxs[4][32];
    const int l = threadIdx.x & 63;
    const int w = threadIdx.x >> 6;
    const int node = blockIdx.x * 4 + w;
    const int b = node >> 11;
    int S = nsp[0]; if (S > 32) S = 32;

    const fvec4* rowp = (const fvec4*)(A + (size_t)node * 2048);
    fvec4 v[8];
#pragma unroll
    for (int c = 0; c < 8; ++c)
        v[c] = __builtin_nontemporal_load(rowp + c * 64 + l);

    int found = 0;
#pragma unroll
    for (int c = 0; c < 8; ++c) {
        if (found >= S) break;                       // wave-uniform
        unsigned long long m0 = __ballot(v[c][0] != 0.f);
        unsigned long long m1 = __ballot(v[c][1] != 0.f);
        unsigned long long m2 = __ballot(v[c][2] != 0.f);
        unsigned long long m3 = __ballot(v[c][3] != 0.f);
        unsigned long long any = m0 | m1 | m2 | m3;
        while (any && found < S) {
            int bl = __builtin_ctzll(any);
            any &= any - 1;
            unsigned long long bit = 1ull << bl;
            int e = (c << 8) + (bl << 2);            // ascending element idx
            if ((m0 & bit) && found < S) { if (l == 0) idxs[w][found] = e;     ++found; }
            if ((m1 & bit) && found < S) { if (l == 0) idxs[w][found] = e + 1; ++found; }
            if ((m2 & bit) && found < S) { if (l == 0) idxs[w][found] = e + 2; ++found; }
            if ((m3 & bit) && found < S) { if (l == 0) idxs[w][found] = e + 3; ++found; }
        }
    }

    float i0 = fmaxf(ba[2 * l], 0.f), i1 = fmaxf(ba[2 * l + 1], 0.f);
    float a0[4] = {i0, i0, i0, i0}, a1[4] = {i1, i1, i1, i1};
    const uint* HB = Hu + ((size_t)b << 17);         // b*2048*64
    int j = 0;
    for (; j + 4 <= found; j += 4) {
        int n0 = idxs[w][j], n1 = idxs[w][j + 1];
        int n2 = idxs[w][j + 2], n3 = idxs[w][j + 3];
        uint h0 = HB[(size_t)n0 * 64 + l];
        uint h1 = HB[(size_t)n1 * 64 + l];
        uint h2 = HB[(size_t)n2 * 64 + l];
        uint h3 = HB[(size_t)n3 * 64 + l];
        a0[0] = fmaxf(a0[0], bflo(h0)); a1[0] = fmaxf(a1[0], bfhi(h0));
        a0[1] = fmaxf(a0[1], bflo(h1)); a1[1] = fmaxf(a1[1], bfhi(h1));
        a0[2] = fmaxf(a0[2], bflo(h2)); a1[2] = fmaxf(a1[2], bfhi(h2));
        a0[3] = fmaxf(a0[3], bflo(h3)); a1[3] = fmaxf(a1[3], bfhi(h3));
    }
    for (; j < found; ++j) {
        uint h = HB[(size_t)idxs[w][j] * 64 + l];
        a0[0] = fmaxf(a0[0], bflo(h)); a1[0] = fmaxf(a1[0], bfhi(h));
    }
    float r0 = fmaxf(fmaxf(a0[0], a0[1]), fmaxf(a0[2], a0[3]));
    float r1 = fmaxf(fmaxf(a1[0], a1[1]), fmaxf(a1[2], a1[3]));
    aggu[(size_t)node * 64 + l] = (uint)f2bf(r0) | ((uint)f2bf(r1) << 16);
}

// ---------------------------------------------------------------------------
// K5: per-batch frobenius normalize in place. Each block deterministically
// reduces its batch's 16 partials (redundant but order-fixed), then scales
// its 1024-float4 chunk. div_no_nan: norm==0 -> 0.
// ---------------------------------------------------------------------------
__global__ __launch_bounds__(256) void scale_k(
    float* __restrict__ out, const float* __restrict__ partials)
{
    const int blk = blockIdx.x;
    const int b = blk >> 6;                          // 64 blocks per batch
    float s = 0.f;
#pragma unroll
    for (int i = 0; i < 16; ++i) s += partials[b * 16 + i];
    float norm = sqrtf(s);
    float sc = (norm > 0.f) ? (1.f / norm) : 0.f;
    fvec4* o4 = (fvec4*)out;
    int i0 = blk * 1024 + threadIdx.x;
#pragma unroll
    for (int k = 0; k < 4; ++k) {
        fvec4 v = o4[i0 + k * 256];
        o4[i0 + k * 256] = v * sc;
    }
}

extern "C" void kernel_launch(void* const* d_in, const int* in_sizes, int n_in,
                              void* d_out, int out_size, void* d_ws, size_t ws_size,
                              hipStream_t stream) {
    const float* A  = (const float*)d_in[0];
    const float* X  = (const float*)d_in[1];
    const float* Wa = (const float*)d_in[2];
    const float* ba = (const float*)d_in[3];
    const float* Wc = (const float*)d_in[4];
    const float* bc = (const float*)d_in[5];
    const int*  nsp = (const int*)d_in[6];

    float* out = (float*)d_out;
    char* ws = (char*)d_ws;
    ushort* H        = (ushort*)ws;                              // 8 MB
    ushort* agg      = (ushort*)(ws + (8u << 20));               // 8 MB
    ushort* Wat      = (ushort*)(ws + (16u << 20));              // 32 KB
    ushort* Wct      = (ushort*)(ws + (16u << 20) + 32768);      // 64 KB
    float*  partials = (float*) (ws + (16u << 20) + 131072);     // 1 KB

    // weights -> bf16 transposed
    prep_w_k<<<192, 256, 0, stream>>>(Wa, Wc, Wat, Wct);
    // K1: H = relu(X @ Wa + ba), bf16
    gemm_mfma_k<<<256, 256, 0, stream>>>(X, nullptr, Wat, ba, H, nullptr, nullptr, 1);
    // K2: agg = max over first-S neighbors
    agg_k<<<8192, 256, 0, stream>>>(A, (const uint*)H, ba, (uint*)agg, nsp);
    // K3: out = relu([X|agg] @ Wc + bc) + partial sumsq
    gemm_mfma_k<<<256, 256, 0, stream>>>(X, agg, Wct, bc, nullptr, out, partials, 2);
    // K5: normalize
    scale_k<<<1024, 256, 0, stream>>>(out, partials);
}

// Round 3
// 93.422 us; speedup vs baseline: 1.7431x; 1.0398x over previous
//
#include <hip/hip_runtime.h>

// B=16, N=2048, C=128, S=25, D_AGG=128, D_OUT=128
// in: A[16,2048,2048] f32, X[16,2048,128] f32, Wa[128,128] f32, ba[128] f32,
//     Wc[256,128] f32, bc[128] f32, n_samples i32
// out: [16,2048,128] f32
//
// Pipeline (bf16 MFMA GEMMs):
//   prep_w : Wa -> Wat[d][k] bf16 (transposed)            (64 blocks)
//   K2pre  : blocks >= 8192 of agg_k do Wc -> Wct bf16    (folded launch)
//   K1     : H  = relu(X @ Wa + ba)  -> bf16 [32768][128] (MFMA)
//   K2     : agg = max over first-S neighbors of H rows   (rank-scan + gather)
//   K3     : out = relu([X|agg] @ Wc + bc) -> f32 + partial sumsq (MFMA)
//   K5     : out *= 1/frobnorm per batch (div_no_nan)
//
// ws: H 8MB @0, agg 8MB @8M, Wat 32KB @16M, Wct 64KB @16M+32K, partials @16M+128K

typedef __attribute__((ext_vector_type(8))) short short8;   // bf16x8 raw bits
typedef __attribute__((ext_vector_type(4))) float f32x4;
typedef __attribute__((ext_vector_type(4))) float fvec4;
typedef unsigned int uint;
typedef unsigned short ushort;

__device__ __forceinline__ ushort f2bf(float x) {           // RNE f32->bf16
    uint u = __builtin_bit_cast(uint, x);
    u += 0x7FFFu + ((u >> 16) & 1u);
    return (ushort)(u >> 16);
}
__device__ __forceinline__ float bflo(uint h) { uint v = h << 16;         return __builtin_bit_cast(float, v); }
__device__ __forceinline__ float bfhi(uint h) { uint v = h & 0xFFFF0000u; return __builtin_bit_cast(float, v); }

// ---------------------------------------------------------------------------
// prep_w: Wat[d*128+k] = bf16(Wa[k][d])  (16384 elems, 64 blocks)
// ---------------------------------------------------------------------------
__global__ __launch_bounds__(256) void prep_w_k(
    const float* __restrict__ Wa, ushort* __restrict__ Wat)
{
    int i = blockIdx.x * 256 + threadIdx.x;     // < 16384
    int d = i >> 7, k = i & 127;
    Wat[i] = f2bf(Wa[k * 128 + d]);
}

// ---------------------------------------------------------------------------
// MFMA GEMM: 128x128 tile/block, 4 waves 2x2, wave = 64x64 = 4x4 frags of
// 16x16x32. Chunk0 converted from fp32, chunk1 (K3) bf16. B pre-transposed
// [col][k]. LDS XOR swizzle on 16B granules (write AND read).
// ---------------------------------------------------------------------------
__global__ __launch_bounds__(256) void gemm_mfma_k(
    const float*  __restrict__ Xf,       // fp32 A source, chunk 0
    const ushort* __restrict__ A1,       // bf16 A source, chunk 1 (or null)
    const ushort* __restrict__ Bt,       // [128][KT] bf16
    const float*  __restrict__ bias,     // [128]
    ushort* __restrict__ outH,           // bf16 out (K1) or null
    float*  __restrict__ outF,           // f32 out (K3) or null
    float*  __restrict__ partials,       // [gridDim.x] sumsq or null
    int ktiles)
{
    __shared__ ushort Asm[128 * 128];
    __shared__ ushort Bsm[128 * 128];
    __shared__ float wred[4];
    const int tid = threadIdx.x;
    const int l = tid & 63, w = tid >> 6;
    const int wm = (w >> 1) * 64, wn = (w & 1) * 64;
    const size_t row0 = (size_t)blockIdx.x * 128;
    const int KT = ktiles << 7;

    f32x4 acc[4][4] = {};

    for (int t = 0; t < ktiles; ++t) {
        __syncthreads();
        if (t == 0) {
#pragma unroll
            for (int j = 0; j < 8; ++j) {
                int gid = (j << 8) + tid;          // 16B granule id
                int r = gid >> 4, g = gid & 15;
                const float* s = Xf + (row0 + r) * 128 + g * 8;
                short8 pk;
#pragma unroll
                for (int e = 0; e < 8; ++e) pk[e] = (short)f2bf(s[e]);
                *(short8*)&Asm[r * 128 + ((g ^ (r & 7)) << 3)] = pk;
            }
        } else {
#pragma unroll
            for (int j = 0; j < 8; ++j) {
                int gid = (j << 8) + tid;
                int r = gid >> 4, g = gid & 15;
                short8 v = *(const short8*)(A1 + (row0 + r) * 128 + g * 8);
                *(short8*)&Asm[r * 128 + ((g ^ (r & 7)) << 3)] = v;
            }
        }
#pragma unroll
        for (int j = 0; j < 8; ++j) {
            int gid = (j << 8) + tid;
            int r = gid >> 4, g = gid & 15;
            short8 v = *(const short8*)(Bt + (size_t)r * KT + (t << 7) + g * 8);
            *(short8*)&Bsm[r * 128 + ((g ^ (r & 7)) << 3)] = v;
        }
        __syncthreads();
#pragma unroll
        for (int ks = 0; ks < 4; ++ks) {
            int gg = (ks << 2) + (l >> 4);
            short8 af[4], bfr[4];
#pragma unroll
            for (int m = 0; m < 4; ++m) {
                int r = wm + m * 16 + (l & 15);
                af[m] = *(const short8*)&Asm[r * 128 + ((gg ^ (r & 7)) << 3)];
            }
#pragma unroll
            for (int n = 0; n < 4; ++n) {
                int c = wn + n * 16 + (l & 15);
                bfr[n] = *(const short8*)&Bsm[c * 128 + ((gg ^ (c & 7)) << 3)];
            }
#pragma unroll
            for (int m = 0; m < 4; ++m)
#pragma unroll
                for (int n = 0; n < 4; ++n)
                    acc[m][n] = __builtin_amdgcn_mfma_f32_16x16x32_bf16(
                        af[m], bfr[n], acc[m][n], 0, 0, 0);
        }
    }

    float bcol[4];
#pragma unroll
    for (int n = 0; n < 4; ++n) bcol[n] = bias[wn + n * 16 + (l & 15)];
    float lsum = 0.f;
#pragma unroll
    for (int m = 0; m < 4; ++m) {
        int rbase = wm + m * 16 + ((l >> 4) << 2);   // C/D: row = 4*(l>>4)+reg
#pragma unroll
        for (int n = 0; n < 4; ++n) {
            int col = wn + n * 16 + (l & 15);        // C/D: col = l&15
#pragma unroll
            for (int r = 0; r < 4; ++r) {
                float v = fmaxf(acc[m][n][r] + bcol[n], 0.f);
                size_t o = (row0 + rbase + r) * 128 + col;
                if (outH) outH[o] = f2bf(v);
                else { outF[o] = v; lsum += v * v; }
            }
        }
    }
    if (partials) {
#pragma unroll
        for (int off = 32; off > 0; off >>= 1) lsum += __shfl_down(lsum, off);
        if (l == 0) wred[w] = lsum;
        __syncthreads();
        if (tid == 0) partials[blockIdx.x] = wred[0] + wred[1] + wred[2] + wred[3];
    }
}

// ---------------------------------------------------------------------------
// K2: one wave per node.
//  Phase 0 (blocks >= 8192): Wct[d*256+k] = bf16(Wc[k][d]) for K3.
//  Phase 1: rank-based parallel scan — per 256-elem chunk, 4 ballots; each
//    nonzero element's rank = chunk base + popcount(masks & lanemask_lt) +
//    own earlier comps. Ranks are the ascending-index order, so rank<S
//    selects exactly lax.top_k's first min(deg,S) indices. Scatter to LDS.
//  Phase 2: pad index list to 8 with idxs[0] (max idempotent), gather-max
//    H rows in uniform 8-deep load rounds. acc init = relu(ba) (= padded
//    slot value). A loads nontemporal (stream, keep H in L2).
// ---------------------------------------------------------------------------
__global__ __launch_bounds__(256) void agg_k(
    const float* __restrict__ A,        // [32768][2048]
    const uint*  __restrict__ Hu,       // [32768][64] (bf16 pairs)
    const float* __restrict__ ba,
    uint* __restrict__ aggu,            // [32768][64] (bf16 pairs)
    const int* __restrict__ nsp,
    const float* __restrict__ Wc,       // for folded prep
    ushort* __restrict__ Wct)
{
    if (blockIdx.x >= 8192) {           // folded Wct prep: 128 blocks
        int j = (blockIdx.x - 8192) * 256 + threadIdx.x;   // < 32768
        int d = j >> 8, k = j & 255;
        Wct[j] = f2bf(Wc[k * 128 + d]);
        return;
    }

    __shared__ int idxs[4][32];
    const int l = threadIdx.x & 63;
    const int w = threadIdx.x >> 6;
    const int node = blockIdx.x * 4 + w;
    const int b = node >> 11;
    int S = nsp[0]; if (S > 32) S = 32;

    const fvec4* rowp = (const fvec4*)(A + (size_t)node * 2048);
    fvec4 v[8];
#pragma unroll
    for (int c = 0; c < 8; ++c)
        v[c] = __builtin_nontemporal_load(rowp + c * 64 + l);

    const unsigned long long lt = (1ull << l) - 1ull;
    int base = 0;
#pragma unroll
    for (int c = 0; c < 8; ++c) {
        if (base < S) {                              // wave-uniform skip
            unsigned long long m0 = __ballot(v[c][0] != 0.f);
            unsigned long long m1 = __ballot(v[c][1] != 0.f);
            unsigned long long m2 = __ballot(v[c][2] != 0.f);
            unsigned long long m3 = __ballot(v[c][3] != 0.f);
            int below = __popcll(m0 & lt) + __popcll(m1 & lt)
                      + __popcll(m2 & lt) + __popcll(m3 & lt);
            int o0 = (int)((m0 >> l) & 1), o1 = (int)((m1 >> l) & 1);
            int o2 = (int)((m2 >> l) & 1), o3 = (int)((m3 >> l) & 1);
            int r0 = base + below;
            int r1 = r0 + o0, r2 = r1 + o1, r3 = r2 + o2;
            int e = (c << 8) + (l << 2);
            if (o0 && r0 < S) idxs[w][r0] = e;
            if (o1 && r1 < S) idxs[w][r1] = e + 1;
            if (o2 && r2 < S) idxs[w][r2] = e + 2;
            if (o3 && r3 < S) idxs[w][r3] = e + 3;
            base += __popcll(m0) + __popcll(m1) + __popcll(m2) + __popcll(m3);
        }
    }
    int found = base < S ? base : S;

    float i0 = fmaxf(ba[2 * l], 0.f), i1 = fmaxf(ba[2 * l + 1], 0.f);
    float r0f, r1f;
    if (found > 0) {
        int fill = idxs[w][0];                       // broadcast read
        if (l < 32) {                                // pad to round multiple
            int val = (l < found) ? idxs[w][l] : fill;
            idxs[w][l] = val;
        }
        int rounds = (found + 7) >> 3;
        float a0[8], a1[8];
#pragma unroll
        for (int q = 0; q < 8; ++q) { a0[q] = i0; a1[q] = i1; }
        const uint* HB = Hu + ((size_t)b << 17);     // b*2048*64
        for (int rr = 0; rr < rounds; ++rr) {        // wave-uniform trip
            int jb = rr << 3;
            uint h[8];
#pragma unroll
            for (int q = 0; q < 8; ++q)
                h[q] = HB[(size_t)idxs[w][jb + q] * 64 + l];
#pragma unroll
            for (int q = 0; q < 8; ++q) {
                a0[q] = fmaxf(a0[q], bflo(h[q]));
                a1[q] = fmaxf(a1[q], bfhi(h[q]));
            }
        }
#pragma unroll
        for (int q = 0; q < 4; ++q) {
            a0[q] = fmaxf(a0[q], a0[q + 4]);
            a1[q] = fmaxf(a1[q], a1[q + 4]);
        }
        r0f = fmaxf(fmaxf(a0[0], a0[1]), fmaxf(a0[2], a0[3]));
        r1f = fmaxf(fmaxf(a1[0], a1[1]), fmaxf(a1[2], a1[3]));
    } else {
        r0f = i0; r1f = i1;
    }
    aggu[(size_t)node * 64 + l] = (uint)f2bf(r0f) | ((uint)f2bf(r1f) << 16);
}

// ---------------------------------------------------------------------------
// K5: per-batch frobenius normalize in place; each block deterministically
// reduces its batch's 16 partials. div_no_nan: norm==0 -> 0.
// ---------------------------------------------------------------------------
__global__ __launch_bounds__(256) void scale_k(
    float* __restrict__ out, const float* __restrict__ partials)
{
    const int blk = blockIdx.x;
    const int b = blk >> 6;                          // 64 blocks per batch
    float s = 0.f;
#pragma unroll
    for (int i = 0; i < 16; ++i) s += partials[b * 16 + i];
    float norm = sqrtf(s);
    float sc = (norm > 0.f) ? (1.f / norm) : 0.f;
    fvec4* o4 = (fvec4*)out;
    int i0 = blk * 1024 + threadIdx.x;
#pragma unroll
    for (int k = 0; k < 4; ++k) {
        fvec4 v = o4[i0 + k * 256];
        o4[i0 + k * 256] = v * sc;
    }
}

extern "C" void kernel_launch(void* const* d_in, const int* in_sizes, int n_in,
                              void* d_out, int out_size, void* d_ws, size_t ws_size,
                              hipStream_t stream) {
    const float* A  = (const float*)d_in[0];
    const float* X  = (const float*)d_in[1];
    const float* Wa = (const float*)d_in[2];
    const float* ba = (const float*)d_in[3];
    const float* Wc = (const float*)d_in[4];
    const float* bc = (const float*)d_in[5];
    const int*  nsp = (const int*)d_in[6];

    float* out = (float*)d_out;
    char* ws = (char*)d_ws;
    ushort* H        = (ushort*)ws;                              // 8 MB
    ushort* agg      = (ushort*)(ws + (8u << 20));               // 8 MB
    ushort* Wat      = (ushort*)(ws + (16u << 20));              // 32 KB
    ushort* Wct      = (ushort*)(ws + (16u << 20) + 32768);      // 64 KB
    float*  partials = (float*) (ws + (16u << 20) + 131072);     // 1 KB

    // Wa -> bf16 transposed
    prep_w_k<<<64, 256, 0, stream>>>(Wa, Wat);
    // K1: H = relu(X @ Wa + ba), bf16
    gemm_mfma_k<<<256, 256, 0, stream>>>(X, nullptr, Wat, ba, H, nullptr, nullptr, 1);
    // K2: agg = max over first-S neighbors (+ folded Wct prep in blocks >= 8192)
    agg_k<<<8192 + 128, 256, 0, stream>>>(A, (const uint*)H, ba, (uint*)agg, nsp, Wc, Wct);
    // K3: out = relu([X|agg] @ Wc + bc) + partial sumsq
    gemm_mfma_k<<<256, 256, 0, stream>>>(X, agg, Wct, bc, nullptr, out, partials, 2);
    // K5: normalize
    scale_k<<<1024, 256, 0, stream>>>(out, partials);
}

// Round 4
// 89.043 us; speedup vs baseline: 1.8288x; 1.0492x over previous
//
#include <hip/hip_runtime.h>

// B=16, N=2048, C=128, S=25, D_AGG=128, D_OUT=128
// in: A[16,2048,2048] f32, X[16,2048,128] f32, Wa[128,128] f32, ba[128] f32,
//     Wc[256,128] f32, bc[128] f32, n_samples i32
// out: [16,2048,128] f32
//
// Pipeline (bf16 MFMA GEMMs):
//   prep_w : Wa -> Wat[d][k] bf16 (transposed)            (64 blocks)
//   K1     : H  = relu(X @ Wa + ba)  -> bf16 [32768][128] (MFMA)
//   K2     : agg = max over first-S neighbors of H rows   (rank-scan + gather)
//            + blocks >= 8192 prep Wc -> Wct bf16
//            batch-affine XCD mapping keeps each batch's H slice in one L2
//   K3     : out = relu([X|agg] @ Wc + bc) -> f32 + partial sumsq (MFMA)
//   K5     : out *= 1/frobnorm per batch (div_no_nan)
//
// ws: H 8MB @0, agg 8MB @8M, Wat 32KB @16M, Wct 64KB @16M+32K, partials @16M+128K

typedef __attribute__((ext_vector_type(8))) short short8;   // bf16x8 raw bits
typedef __attribute__((ext_vector_type(4))) float f32x4;
typedef __attribute__((ext_vector_type(4))) float fvec4;
typedef unsigned int uint;
typedef unsigned short ushort;

__device__ __forceinline__ ushort f2bf(float x) {           // RNE f32->bf16
    uint u = __builtin_bit_cast(uint, x);
    u += 0x7FFFu + ((u >> 16) & 1u);
    return (ushort)(u >> 16);
}
__device__ __forceinline__ float bflo(uint h) { uint v = h << 16;         return __builtin_bit_cast(float, v); }
__device__ __forceinline__ float bfhi(uint h) { uint v = h & 0xFFFF0000u; return __builtin_bit_cast(float, v); }

// ---------------------------------------------------------------------------
// prep_w: Wat[d*128+k] = bf16(Wa[k][d])  (16384 elems, 64 blocks)
// ---------------------------------------------------------------------------
__global__ __launch_bounds__(256) void prep_w_k(
    const float* __restrict__ Wa, ushort* __restrict__ Wat)
{
    int i = blockIdx.x * 256 + threadIdx.x;     // < 16384
    int d = i >> 7, k = i & 127;
    Wat[i] = f2bf(Wa[k * 128 + d]);
}

// ---------------------------------------------------------------------------
// MFMA GEMM: 128x128 tile/block, 4 waves 2x2, wave = 64x64 = 4x4 frags of
// 16x16x32. Chunk0 converted from fp32, chunk1 (K3) bf16. B pre-transposed
// [col][k]. LDS XOR swizzle on 16B granules (write AND read).
// ---------------------------------------------------------------------------
__global__ __launch_bounds__(256) void gemm_mfma_k(
    const float*  __restrict__ Xf,       // fp32 A source, chunk 0
    const ushort* __restrict__ A1,       // bf16 A source, chunk 1 (or null)
    const ushort* __restrict__ Bt,       // [128][KT] bf16
    const float*  __restrict__ bias,     // [128]
    ushort* __restrict__ outH,           // bf16 out (K1) or null
    float*  __restrict__ outF,           // f32 out (K3) or null
    float*  __restrict__ partials,       // [gridDim.x] sumsq or null
    int ktiles)
{
    __shared__ ushort Asm[128 * 128];
    __shared__ ushort Bsm[128 * 128];
    __shared__ float wred[4];
    const int tid = threadIdx.x;
    const int l = tid & 63, w = tid >> 6;
    const int wm = (w >> 1) * 64, wn = (w & 1) * 64;
    const size_t row0 = (size_t)blockIdx.x * 128;
    const int KT = ktiles << 7;

    f32x4 acc[4][4] = {};

    for (int t = 0; t < ktiles; ++t) {
        __syncthreads();
        if (t == 0) {
#pragma unroll
            for (int j = 0; j < 8; ++j) {
                int gid = (j << 8) + tid;          // 16B granule id
                int r = gid >> 4, g = gid & 15;
                const float* s = Xf + (row0 + r) * 128 + g * 8;
                short8 pk;
#pragma unroll
                for (int e = 0; e < 8; ++e) pk[e] = (short)f2bf(s[e]);
                *(short8*)&Asm[r * 128 + ((g ^ (r & 7)) << 3)] = pk;
            }
        } else {
#pragma unroll
            for (int j = 0; j < 8; ++j) {
                int gid = (j << 8) + tid;
                int r = gid >> 4, g = gid & 15;
                short8 v = *(const short8*)(A1 + (row0 + r) * 128 + g * 8);
                *(short8*)&Asm[r * 128 + ((g ^ (r & 7)) << 3)] = v;
            }
        }
#pragma unroll
        for (int j = 0; j < 8; ++j) {
            int gid = (j << 8) + tid;
            int r = gid >> 4, g = gid & 15;
            short8 v = *(const short8*)(Bt + (size_t)r * KT + (t << 7) + g * 8);
            *(short8*)&Bsm[r * 128 + ((g ^ (r & 7)) << 3)] = v;
        }
        __syncthreads();
#pragma unroll
        for (int ks = 0; ks < 4; ++ks) {
            int gg = (ks << 2) + (l >> 4);
            short8 af[4], bfr[4];
#pragma unroll
            for (int m = 0; m < 4; ++m) {
                int r = wm + m * 16 + (l & 15);
                af[m] = *(const short8*)&Asm[r * 128 + ((gg ^ (r & 7)) << 3)];
            }
#pragma unroll
            for (int n = 0; n < 4; ++n) {
                int c = wn + n * 16 + (l & 15);
                bfr[n] = *(const short8*)&Bsm[c * 128 + ((gg ^ (c & 7)) << 3)];
            }
#pragma unroll
            for (int m = 0; m < 4; ++m)
#pragma unroll
                for (int n = 0; n < 4; ++n)
                    acc[m][n] = __builtin_amdgcn_mfma_f32_16x16x32_bf16(
                        af[m], bfr[n], acc[m][n], 0, 0, 0);
        }
    }

    float bcol[4];
#pragma unroll
    for (int n = 0; n < 4; ++n) bcol[n] = bias[wn + n * 16 + (l & 15)];
    float lsum = 0.f;
#pragma unroll
    for (int m = 0; m < 4; ++m) {
        int rbase = wm + m * 16 + ((l >> 4) << 2);   // C/D: row = 4*(l>>4)+reg
#pragma unroll
        for (int n = 0; n < 4; ++n) {
            int col = wn + n * 16 + (l & 15);        // C/D: col = l&15
#pragma unroll
            for (int r = 0; r < 4; ++r) {
                float v = fmaxf(acc[m][n][r] + bcol[n], 0.f);
                size_t o = (row0 + rbase + r) * 128 + col;
                if (outH) outH[o] = f2bf(v);
                else { outF[o] = v; lsum += v * v; }
            }
        }
    }
    if (partials) {
#pragma unroll
        for (int off = 32; off > 0; off >>= 1) lsum += __shfl_down(lsum, off);
        if (l == 0) wred[w] = lsum;
        __syncthreads();
        if (tid == 0) partials[blockIdx.x] = wred[0] + wred[1] + wred[2] + wred[3];
    }
}

// ---------------------------------------------------------------------------
// K2: one wave per node.
//  Block mapping is batch-affine per XCD (XCD = bid&7 heuristic): batch =
//  (grp>>9)*8 + (bid&7), so one XCD touches only 2 batches' H slices (1 MB)
//  -> H gathers are L2 hits; each H line fetched from HBM ~once.
//  Phase 1: rank-based ballot scan -> first min(deg,S) ascending indices
//  to LDS (== lax.top_k of binary mask).
//  Phase 2: pad index list to 32 with idxs[0] (max idempotent) and issue all
//  32 gathers branch-free -> full L2-latency overlap, one vmcnt drain.
//  acc init = relu(ba) (= padded slot value). A loads nontemporal.
//  Blocks >= 8192: Wct[d*256+k] = bf16(Wc[k][d]) prep for K3.
// ---------------------------------------------------------------------------
__global__ __launch_bounds__(256) void agg_k(
    const float* __restrict__ A,        // [32768][2048]
    const uint*  __restrict__ Hu,       // [32768][64] (bf16 pairs)
    const float* __restrict__ ba,
    uint* __restrict__ aggu,            // [32768][64] (bf16 pairs)
    const int* __restrict__ nsp,
    const float* __restrict__ Wc,       // for folded prep
    ushort* __restrict__ Wct)
{
    if (blockIdx.x >= 8192) {           // folded Wct prep: 128 blocks
        int j = (blockIdx.x - 8192) * 256 + threadIdx.x;   // < 32768
        int d = j >> 8, k = j & 255;
        Wct[j] = f2bf(Wc[k * 128 + d]);
        return;
    }

    __shared__ int idxs[4][32];
    const int l = threadIdx.x & 63;
    const int w = threadIdx.x >> 6;
    // batch-affine XCD mapping
    const int bid   = blockIdx.x;
    const int xcd   = bid & 7;
    const int grp   = bid >> 3;                  // 0..1023
    const int batch = ((grp >> 9) << 3) + xcd;   // 0..15
    const int node  = (batch << 11) + ((grp & 511) << 2) + w;
    int S = nsp[0]; if (S > 32) S = 32;

    const fvec4* rowp = (const fvec4*)(A + (size_t)node * 2048);
    fvec4 v[8];
#pragma unroll
    for (int c = 0; c < 8; ++c)
        v[c] = __builtin_nontemporal_load(rowp + c * 64 + l);

    const unsigned long long lt = (1ull << l) - 1ull;
    int base = 0;
#pragma unroll
    for (int c = 0; c < 8; ++c) {
        if (base < S) {                              // wave-uniform skip
            unsigned long long m0 = __ballot(v[c][0] != 0.f);
            unsigned long long m1 = __ballot(v[c][1] != 0.f);
            unsigned long long m2 = __ballot(v[c][2] != 0.f);
            unsigned long long m3 = __ballot(v[c][3] != 0.f);
            int below = __popcll(m0 & lt) + __popcll(m1 & lt)
                      + __popcll(m2 & lt) + __popcll(m3 & lt);
            int o0 = (int)((m0 >> l) & 1), o1 = (int)((m1 >> l) & 1);
            int o2 = (int)((m2 >> l) & 1), o3 = (int)((m3 >> l) & 1);
            int r0 = base + below;
            int r1 = r0 + o0, r2 = r1 + o1, r3 = r2 + o2;
            int e = (c << 8) + (l << 2);
            if (o0 && r0 < S) idxs[w][r0] = e;
            if (o1 && r1 < S) idxs[w][r1] = e + 1;
            if (o2 && r2 < S) idxs[w][r2] = e + 2;
            if (o3 && r3 < S) idxs[w][r3] = e + 3;
            base += __popcll(m0) + __popcll(m1) + __popcll(m2) + __popcll(m3);
        }
    }
    int found = base < S ? base : S;

    float i0 = fmaxf(ba[2 * l], 0.f), i1 = fmaxf(ba[2 * l + 1], 0.f);
    float r0f = i0, r1f = i1;
    if (found > 0) {
        int fill = idxs[w][0];                       // broadcast read
        if (l < 32)                                  // pad list to 32
            idxs[w][l] = (l < found) ? idxs[w][l] : fill;
        // same-wave LDS write->read: in-order, compiler inserts lgkmcnt

        const uint* HB = Hu + ((size_t)batch << 17); // batch*2048*64
        uint h[32];
#pragma unroll
        for (int q = 0; q < 32; ++q)                 // all 32 in flight
            h[q] = HB[(size_t)idxs[w][q] * 64 + l];

        float a0[8], a1[8];
#pragma unroll
        for (int q = 0; q < 8; ++q) { a0[q] = i0; a1[q] = i1; }
#pragma unroll
        for (int q = 0; q < 32; ++q) {
            a0[q & 7] = fmaxf(a0[q & 7], bflo(h[q]));
            a1[q & 7] = fmaxf(a1[q & 7], bfhi(h[q]));
        }
#pragma unroll
        for (int q = 0; q < 4; ++q) {
            a0[q] = fmaxf(a0[q], a0[q + 4]);
            a1[q] = fmaxf(a1[q], a1[q + 4]);
        }
        r0f = fmaxf(fmaxf(a0[0], a0[1]), fmaxf(a0[2], a0[3]));
        r1f = fmaxf(fmaxf(a1[0], a1[1]), fmaxf(a1[2], a1[3]));
    }
    aggu[(size_t)node * 64 + l] = (uint)f2bf(r0f) | ((uint)f2bf(r1f) << 16);
}

// ---------------------------------------------------------------------------
// K5: per-batch frobenius normalize in place; each block deterministically
// reduces its batch's 16 partials. div_no_nan: norm==0 -> 0.
// ---------------------------------------------------------------------------
__global__ __launch_bounds__(256) void scale_k(
    float* __restrict__ out, const float* __restrict__ partials)
{
    const int blk = blockIdx.x;
    const int b = blk >> 6;                          // 64 blocks per batch
    float s = 0.f;
#pragma unroll
    for (int i = 0; i < 16; ++i) s += partials[b * 16 + i];
    float norm = sqrtf(s);
    float sc = (norm > 0.f) ? (1.f / norm) : 0.f;
    fvec4* o4 = (fvec4*)out;
    int i0 = blk * 1024 + threadIdx.x;
#pragma unroll
    for (int k = 0; k < 4; ++k) {
        fvec4 v = o4[i0 + k * 256];
        o4[i0 + k * 256] = v * sc;
    }
}

extern "C" void kernel_launch(void* const* d_in, const int* in_sizes, int n_in,
                              void* d_out, int out_size, void* d_ws, size_t ws_size,
                              hipStream_t stream) {
    const float* A  = (const float*)d_in[0];
    const float* X  = (const float*)d_in[1];
    const float* Wa = (const float*)d_in[2];
    const float* ba = (const float*)d_in[3];
    const float* Wc = (const float*)d_in[4];
    const float* bc = (const float*)d_in[5];
    const int*  nsp = (const int*)d_in[6];

    float* out = (float*)d_out;
    char* ws = (char*)d_ws;
    ushort* H        = (ushort*)ws;                              // 8 MB
    ushort* agg      = (ushort*)(ws + (8u << 20));               // 8 MB
    ushort* Wat      = (ushort*)(ws + (16u << 20));              // 32 KB
    ushort* Wct      = (ushort*)(ws + (16u << 20) + 32768);      // 64 KB
    float*  partials = (float*) (ws + (16u << 20) + 131072);     // 1 KB

    // Wa -> bf16 transposed
    prep_w_k<<<64, 256, 0, stream>>>(Wa, Wat);
    // K1: H = relu(X @ Wa + ba), bf16
    gemm_mfma_k<<<256, 256, 0, stream>>>(X, nullptr, Wat, ba, H, nullptr, nullptr, 1);
    // K2: agg = max over first-S neighbors (+ folded Wct prep in blocks >= 8192)
    agg_k<<<8192 + 128, 256, 0, stream>>>(A, (const uint*)H, ba, (uint*)agg, nsp, Wc, Wct);
    // K3: out = relu([X|agg] @ Wc + bc) + partial sumsq
    gemm_mfma_k<<<256, 256, 0, stream>>>(X, agg, Wct, bc, nullptr, out, partials, 2);
    // K5: normalize
    scale_k<<<1024, 256, 0, stream>>>(out, partials);
}